// Round 13
// baseline (479.974 us; speedup 1.0000x reference)
//
#include <hip/hip_runtime.h>

#define NTOK 16384
#define DIM  128
#define NJT  128   // number of 128-wide j tiles
#define RB   64    // i-rows per attn block

typedef __attribute__((ext_vector_type(8))) short short8;
typedef __attribute__((ext_vector_type(4))) float f32x4;
typedef __attribute__((ext_vector_type(4))) int   i32x4;
typedef __attribute__((address_space(1))) void void_g;
typedef __attribute__((address_space(3))) void void_l;

// fold 1/sqrt(128) * log2(e) into Q so scores come out in log2 domain
#define QSCALE (1.4426950408889634f * 0.08838834764831845f)

__device__ __forceinline__ short f2bf(float f) {
  union { float f; unsigned u; } v; v.f = f;
  return (short)((v.u + 0x7FFFu + ((v.u >> 16) & 1u)) >> 16);
}

// packed f32x2 -> bf16x2, single VALU op
__device__ __forceinline__ unsigned pkbf2(float a, float b) {
  unsigned r;
  asm("v_cvt_pk_bf16_f32 %0, %1, %2" : "=v"(r) : "v"(a), "v"(b));
  return r;
}

__device__ __forceinline__ short8 pack8(const float4 a, const float4 b) {
  union { unsigned u[4]; short8 s; } r;
  r.u[0] = pkbf2(a.x, a.y);
  r.u[1] = pkbf2(a.z, a.w);
  r.u[2] = pkbf2(b.x, b.y);
  r.u[3] = pkbf2(b.z, b.w);
  return r.s;
}

__device__ __forceinline__ void gload16(char* l, const char* g) {
  __builtin_amdgcn_global_load_lds((void_g*)g, (void_l*)l, 16, 0, 0);
}

__device__ __forceinline__ float bf2f(short s) {
  union { float f; unsigned u; } v;
  v.u = ((unsigned)(unsigned short)s) << 16;
  return v.f;
}

// ---------------------------------------------------------------------------
// Kernel 1 (prep): blocks 0..255 = QKV projection (unchanged layouts);
// blocks 256.. = adj bit-pack with fully-contiguous HBM reads.
//  Qb: [N][128] bf16 row-major, pre-scaled by QSCALE
//  K3 (bf16): A-frag chunks, tile t = 32KB; chunk(jfg,kf)=1KB; lane l holds
//      K[t*128 + jfg*16 + (l&15)][kf*32 + (l>>4)*8 .. +8] at lane*16
//  V8 (fp8 e4m3): tile t = 16KB; chunk(jg,d) = 8B = V[t*128+jg*8 .. +8][d]
//  PB (packed adj): [t 128][i 16384] x 16B; dword e (e=0..3) holds bits for
//      tile-cols {4k+e}, bit k. So col j=4k+e -> dword e, bit k.
// ---------------------------------------------------------------------------
__device__ __forceinline__ void mm16(const short8 (&af)[4], const float* __restrict__ W,
                                     const float* __restrict__ b, int l15, int lg,
                                     f32x4 (&acc)[8], float (&bias)[8]) {
#pragma unroll
  for (int nf = 0; nf < 8; ++nf) {
    acc[nf][0] = 0.f; acc[nf][1] = 0.f; acc[nf][2] = 0.f; acc[nf][3] = 0.f;
  }
#pragma unroll
  for (int kf = 0; kf < 4; ++kf) {
#pragma unroll
    for (int nf = 0; nf < 8; ++nf) {
      const float* wp = W + (size_t)(nf * 16 + l15) * DIM + kf * 32 + lg * 8;
      short8 bfr = pack8(*(const float4*)wp, *(const float4*)(wp + 4));
      acc[nf] = __builtin_amdgcn_mfma_f32_16x16x32_bf16(af[kf], bfr, acc[nf], 0, 0, 0);
    }
  }
#pragma unroll
  for (int nf = 0; nf < 8; ++nf) bias[nf] = b[nf * 16 + l15];
}

__global__ __launch_bounds__(256) void prep_kernel(
    const float* __restrict__ X,
    const float* __restrict__ Wq, const float* __restrict__ bq,
    const float* __restrict__ Wk, const float* __restrict__ bk,
    const float* __restrict__ Wv, const float* __restrict__ bv,
    const int* __restrict__ adj,
    short* __restrict__ Qb, char* __restrict__ K3, char* __restrict__ V8,
    char* __restrict__ PB) {
  __shared__ short ktile[64][136];
  __shared__ short vtile[64][136];

  const int tid = threadIdx.x;
  const int w = tid >> 6, lane = tid & 63;

  if (blockIdx.x >= 256) {
    // ---------------- adj bit-pack ----------------
    const int pid = blockIdx.x - 256;          // 0..2047
    const int wg = pid * 4 + w;                // 0..8191
#pragma unroll
    for (int rr = 0; rr < 2; ++rr) {
      const int row = wg * 2 + rr;
      const int* base = adj + (size_t)row * NTOK;
      for (int seg = 0; seg < 64; ++seg) {
        const int cb = seg * 256;              // 256 cols = 2 tiles per pass
        const i32x4 v = *(const i32x4*)(base + cb + lane * 4);
        const unsigned long long b0 = __ballot(v[0] != 0);
        const unsigned long long b1 = __ballot(v[1] != 0);
        const unsigned long long b2 = __ballot(v[2] != 0);
        const unsigned long long b3 = __ballot(v[3] != 0);
        if (lane == 0) {
          i32x4 o;
          o[0] = (int)(unsigned)b0; o[1] = (int)(unsigned)b1;
          o[2] = (int)(unsigned)b2; o[3] = (int)(unsigned)b3;
          *(i32x4*)(PB + ((size_t)(cb >> 7) * NTOK + row) * 16) = o;
        } else if (lane == 32) {
          i32x4 o;
          o[0] = (int)(b0 >> 32); o[1] = (int)(b1 >> 32);
          o[2] = (int)(b2 >> 32); o[3] = (int)(b3 >> 32);
          *(i32x4*)(PB + ((size_t)((cb >> 7) + 1) * NTOK + row) * 16) = o;
        }
      }
    }
    return;
  }

  // ---------------- QKV projection (unchanged from R7) ----------------
  const int l15 = lane & 15, lg = lane >> 4;
  const int i0 = blockIdx.x * 64;
  const int t = i0 >> 7, jl0 = i0 & 127;

  short8 af[4];
  {
    const int xrow = i0 + w * 16 + l15;
#pragma unroll
    for (int kf = 0; kf < 4; ++kf) {
      const float* xp = X + (size_t)xrow * DIM + kf * 32 + lg * 8;
      af[kf] = pack8(*(const float4*)xp, *(const float4*)(xp + 4));
    }
  }

  f32x4 acc[8];
  float bias[8];

  // ---- Q ----
  mm16(af, Wq, bq, l15, lg, acc, bias);
#pragma unroll
  for (int nf = 0; nf < 8; ++nf) {
    const int d = nf * 16 + l15;
#pragma unroll
    for (int rr = 0; rr < 4; ++rr) {
      const int i = i0 + w * 16 + lg * 4 + rr;
      Qb[(size_t)i * DIM + d] = f2bf((acc[nf][rr] + bias[nf]) * QSCALE);
    }
  }

  // ---- K ----
  mm16(af, Wk, bk, l15, lg, acc, bias);
#pragma unroll
  for (int nf = 0; nf < 8; ++nf) {
    const int d = nf * 16 + l15;
#pragma unroll
    for (int rr = 0; rr < 4; ++rr)
      ktile[w * 16 + lg * 4 + rr][d] = f2bf(acc[nf][rr] + bias[nf]);
  }

  // ---- V ----
  mm16(af, Wv, bv, l15, lg, acc, bias);
#pragma unroll
  for (int nf = 0; nf < 8; ++nf) {
    const int d = nf * 16 + l15;
#pragma unroll
    for (int rr = 0; rr < 4; ++rr)
      vtile[w * 16 + lg * 4 + rr][d] = f2bf(acc[nf][rr] + bias[nf]);
  }
  __syncthreads();

  // K3 chunks (bf16): task = chunk o (0..15) x local row (0..63)
#pragma unroll
  for (int it = 0; it < 4; ++it) {
    const int task = it * 256 + tid;
    const int o = task >> 6, jr = task & 63;
    const int j = i0 + jr;
    const int jfg = (j >> 4) & 7;
    const int kf = o >> 2, lgc = o & 3;
    short8 st = *(const short8*)&ktile[jr][o * 8];
    *(short8*)(K3 + ((size_t)((t * 8 + jfg) * 4 + kf) << 10) + lgc * 256 + (j & 15) * 16) = st;
  }

  // V8 chunks (fp8): task = c (8 j-octets) x d (128)
#pragma unroll
  for (int it = 0; it < 4; ++it) {
    const int task = it * 256 + tid;
    const int c = task >> 7, d = task & 127;
    float f[8];
#pragma unroll
    for (int s2 = 0; s2 < 8; ++s2) f[s2] = bf2f(vtile[c * 8 + s2][d]);
    int lo = __builtin_amdgcn_cvt_pk_fp8_f32(f[0], f[1], 0, false);
    lo = __builtin_amdgcn_cvt_pk_fp8_f32(f[2], f[3], lo, true);
    int hi = __builtin_amdgcn_cvt_pk_fp8_f32(f[4], f[5], 0, false);
    hi = __builtin_amdgcn_cvt_pk_fp8_f32(f[6], f[7], hi, true);
    const int jg = (jl0 >> 3) + c;   // j-octet index within tile (0..15)
    *(int2*)(V8 + (((size_t)t * 16 + jg) * 128 + d) * 8) = make_int2(lo, hi);
  }
}

// ---------------------------------------------------------------------------
// Kernel 2: fused masked-softmax attention (R7 base; adj -> packed bits).
// 256 blocks x 1024 threads (16 waves, 4 waves/SIMD at <=128 VGPR).
// Wave (ir, wc): i-rows [ir*16,+16), j-slice [wc*32,+32).
// K (bf16) + V (fp8) double-buffered in LDS via global_load_lds; packed adj
// read 16B/lane/step from L3 (prefetched 1 step ahead). One barrier per step.
// ---------------------------------------------------------------------------
__device__ __forceinline__ void stage_kv(char* kdst, char* vdst,
                                         const char* __restrict__ K3,
                                         const char* __restrict__ V8,
                                         int t, int tid) {
  const char* gk = K3 + ((size_t)t << 15);
  const char* gv = V8 + ((size_t)t << 14);
  const int o = tid * 16;
  gload16(kdst + o,         gk + o);
  gload16(kdst + 16384 + o, gk + 16384 + o);
  gload16(vdst + o,         gv + o);
}

__device__ __forceinline__ i32x4 load_bits(const char* __restrict__ PB,
                                           int t, int i0, int ir, int l15) {
  return *(const i32x4*)(PB + ((size_t)t * NTOK + i0 + ir * 16 + l15) * 16);
}

__device__ __forceinline__ void attn_step(
    int t, const char* kcur, const char* vcur, char* knxt, char* vnxt,
    const char* __restrict__ K3, const char* __restrict__ V8,
    const char* __restrict__ PB,
    const short8 (&qf)[4], f32x4 (&acc)[8], float& dsum,
    const i32x4& bC, i32x4& bN,
    int i0, int ir, int wc, int l15, int lg, int lane, int tid,
    int ad0, bool selhi) {
  const int tn = (t + 1) & (NJT - 1);

  // stage next K/V tile; prefetch next packed-adj row chunk
  stage_kv(knxt, vnxt, K3, V8, tn, tid);
  bN = load_bits(PB, tn, i0, ir, l15);

  // ---- S^T = K @ Q^T : lane holds S[i=l15][j=(wc*2+jf)*16 + lg*4+r] ----
  f32x4 sT[2];
#pragma unroll
  for (int jf = 0; jf < 2; ++jf) {
    sT[jf][0] = 0.f; sT[jf][1] = 0.f; sT[jf][2] = 0.f; sT[jf][3] = 0.f;
  }
#pragma unroll
  for (int jf = 0; jf < 2; ++jf)
#pragma unroll
    for (int kf = 0; kf < 4; ++kf) {
      const short8 kfr = *(const short8*)(kcur + (((wc * 2 + jf) * 4 + kf) << 10) + lane * 16);
      sT[jf] = __builtin_amdgcn_mfma_f32_16x16x32_bf16(kfr, qf[kf], sT[jf], 0, 0, 0);
    }

  // ---- mask (bit k=wc*8+jf*4+lg of dword r) + exp2 (halved) + fp8 pack ----
  int pk8[2];
#pragma unroll
  for (int jf = 0; jf < 2; ++jf) {
    const int kbit = wc * 8 + jf * 4 + lg;
    const float e0 = __builtin_exp2f(sT[jf][0]) * 0.5f;
    const float e1 = __builtin_exp2f(sT[jf][1]) * 0.5f;
    const float e2 = __builtin_exp2f(sT[jf][2]) * 0.5f;
    const float e3 = __builtin_exp2f(sT[jf][3]) * 0.5f;
    const float p0 = ((bC[0] >> kbit) & 1) ? e0 : 0.5f;
    const float p1 = ((bC[1] >> kbit) & 1) ? e1 : 0.5f;
    const float p2 = ((bC[2] >> kbit) & 1) ? e2 : 0.5f;
    const float p3 = ((bC[3] >> kbit) & 1) ? e3 : 0.5f;
    dsum += (p0 + p1) + (p2 + p3);
    int d0 = __builtin_amdgcn_cvt_pk_fp8_f32(p0, p1, 0, false);
    pk8[jf] = __builtin_amdgcn_cvt_pk_fp8_f32(p2, p3, d0, true);
  }

  // ---- in-wave exchange: build fp8 PV A-frag P[i=l15][j=lg*8+e] ----
  union { int2 i2; long l; } pa;
#pragma unroll
  for (int w2 = 0; w2 < 2; ++w2) {
    const int addr = ad0 + w2 * 64;
    const int r0 = __builtin_amdgcn_ds_bpermute(addr, pk8[0]);
    const int r1 = __builtin_amdgcn_ds_bpermute(addr, pk8[1]);
    (w2 ? pa.i2.y : pa.i2.x) = selhi ? r1 : r0;
  }

  // ---- acc += P @ V (fp8 x fp8, this wave's j:32, full d:128) ----
#pragma unroll
  for (int nf = 0; nf < 8; ++nf) {
    const long vb = *(const long*)(vcur + (((wc * 4 + lg) * 128 + nf * 16 + l15) << 3));
    acc[nf] = __builtin_amdgcn_mfma_f32_16x16x32_fp8_fp8(pa.l, vb, acc[nf], 0, 0, 0);
  }

  // barrier (vmcnt0+lgkm0 drain): stage complete, buffers flip
  __syncthreads();
}

__global__ __launch_bounds__(1024, 4) void attn_kernel(
    const short* __restrict__ QbG, const char* __restrict__ K3,
    const char* __restrict__ V8, const char* __restrict__ PB,
    float* __restrict__ out) {
  __shared__ __align__(16) char kbuf[2][32768];   // K bf16 double buffer
  __shared__ __align__(16) char vbuf[2][16384];   // V fp8 double buffer
  __shared__ float denp[4][64];

  const int tid = threadIdx.x;
  const int w = tid >> 6, lane = tid & 63;
  const int l15 = lane & 15, lg = lane >> 4;
  const int ir = w >> 2, wc = w & 3;
  const int i0 = blockIdx.x * RB;

  // bpermute source lane for (w2): lg_src = (lg*2 + w2) & 3; select jf by lg>=2
  const int ad0 = 4 * (l15 + 16 * ((lg * 2) & 3));
  const bool selhi = (lg & 2) != 0;

  // Q B-frags (persist): lane holds Q[i = i0+ir*16+l15][kf*32+lg*8 ..+8]
  short8 qf[4];
  {
    const int i = i0 + ir * 16 + l15;
#pragma unroll
    for (int kf = 0; kf < 4; ++kf)
      qf[kf] = *(const short8*)(QbG + (size_t)i * DIM + kf * 32 + lg * 8);
  }

  f32x4 acc[8];
#pragma unroll
  for (int nf = 0; nf < 8; ++nf) {
    acc[nf][0] = 0.f; acc[nf][1] = 0.f; acc[nf][2] = 0.f; acc[nf][3] = 0.f;
  }
  float dsum = 0.f;
  i32x4 bA, bB;

  stage_kv(kbuf[0], vbuf[0], K3, V8, 0, tid);
  bA = load_bits(PB, 0, i0, ir, l15);
  __syncthreads();

  for (int t = 0; t < NJT; t += 2) {
    attn_step(t,     kbuf[0], vbuf[0], kbuf[1], vbuf[1], K3, V8, PB, qf, acc,
              dsum, bA, bB, i0, ir, wc, l15, lg, lane, tid, ad0, selhi);
    attn_step(t + 1, kbuf[1], vbuf[1], kbuf[0], vbuf[0], K3, V8, PB, qf, acc,
              dsum, bB, bA, i0, ir, wc, l15, lg, lane, tid, ad0, selhi);
  }

  // ---- denominator: lane covers i=l15; sum over lg groups, then wc ----
  float d0 = dsum;
  d0 += __shfl_xor(d0, 16);
  d0 += __shfl_xor(d0, 32);
  if (lg == 0) denp[wc][ir * 16 + l15] = d0;

  // ---- cross-wc acc reduction through LDS (reuse kbuf: 33.8KB/round) ----
  float* red = (float*)kbuf;   // 4 slots x 16 rows x 132 floats
#pragma unroll
  for (int rnd = 1; rnd <= 3; ++rnd) {
    __syncthreads();
    if (wc == rnd) {
      const int base = ir * 16 * 132;
#pragma unroll
      for (int nf = 0; nf < 8; ++nf)
#pragma unroll
        for (int r = 0; r < 4; ++r)
          red[base + (lg * 4 + r) * 132 + nf * 16 + l15] = acc[nf][r];
    }
    __syncthreads();
    if (wc == 0) {
      const int base = ir * 16 * 132;
#pragma unroll
      for (int nf = 0; nf < 8; ++nf)
#pragma unroll
        for (int r = 0; r < 4; ++r)
          acc[nf][r] += red[base + (lg * 4 + r) * 132 + nf * 16 + l15];
    }
  }

  if (wc == 0) {
    float den[4];
#pragma unroll
    for (int r = 0; r < 4; ++r) {
      const int il = ir * 16 + lg * 4 + r;
      den[r] = (denp[0][il] + denp[1][il]) + (denp[2][il] + denp[3][il]);
    }
#pragma unroll
    for (int nf = 0; nf < 8; ++nf)
#pragma unroll
      for (int r = 0; r < 4; ++r) {
        const int i = ir * 16 + lg * 4 + r;
        out[(size_t)(i0 + i) * DIM + nf * 16 + l15] = acc[nf][r] / den[r];
      }
  }
}

// ---------------------------------------------------------------------------
extern "C" void kernel_launch(void* const* d_in, const int* in_sizes, int n_in,
                              void* d_out, int out_size, void* d_ws, size_t ws_size,
                              hipStream_t stream) {
  const float* X  = (const float*)d_in[0];
  const float* Wq = (const float*)d_in[1];
  const float* bq = (const float*)d_in[2];
  const float* Wk = (const float*)d_in[3];
  const float* bk = (const float*)d_in[4];
  const float* Wv = (const float*)d_in[5];
  const float* bv = (const float*)d_in[6];
  const int*  adj = (const int*)d_in[7];
  float* out = (float*)d_out;

  char* ws = (char*)d_ws;
  short* Qb = (short*)ws;                       // 4 MB bf16 [N][128]
  char*  K3 = ws + ((size_t)4 << 20);           // 4 MB A-frag-contiguous K (bf16)
  char*  V8 = ws + ((size_t)8 << 20);           // 2 MB fp8 V^T chunks
  char*  PB = ws + ((size_t)10 << 20);          // 32 MB packed adj bits

  prep_kernel<<<2304, 256, 0, stream>>>(X, Wq, bq, Wk, bk, Wv, bv, adj,
                                        Qb, K3, V8, PB);
  attn_kernel<<<256, 1024, 0, stream>>>(Qb, K3, V8, PB, out);
}

// Round 14
// 347.443 us; speedup vs baseline: 1.3814x; 1.3814x over previous
//
#include <hip/hip_runtime.h>

#define NTOK 16384
#define DIM  128
#define NJT  128   // number of 128-wide j tiles
#define RB   64    // i-rows per attn block

typedef __attribute__((ext_vector_type(8))) short short8;
typedef __attribute__((ext_vector_type(4))) float f32x4;
typedef __attribute__((ext_vector_type(4))) int   i32x4;
typedef __attribute__((address_space(1))) void void_g;
typedef __attribute__((address_space(3))) void void_l;

// fold 1/sqrt(128) * log2(e) into Q so scores come out in log2 domain
#define QSCALE (1.4426950408889634f * 0.08838834764831845f)

__device__ __forceinline__ short f2bf(float f) {
  union { float f; unsigned u; } v; v.f = f;
  return (short)((v.u + 0x7FFFu + ((v.u >> 16) & 1u)) >> 16);
}

// packed f32x2 -> bf16x2, single VALU op
__device__ __forceinline__ unsigned pkbf2(float a, float b) {
  unsigned r;
  asm("v_cvt_pk_bf16_f32 %0, %1, %2" : "=v"(r) : "v"(a), "v"(b));
  return r;
}

__device__ __forceinline__ short8 pack8(const float4 a, const float4 b) {
  union { unsigned u[4]; short8 s; } r;
  r.u[0] = pkbf2(a.x, a.y);
  r.u[1] = pkbf2(a.z, a.w);
  r.u[2] = pkbf2(b.x, b.y);
  r.u[3] = pkbf2(b.z, b.w);
  return r.s;
}

__device__ __forceinline__ void gload16(char* l, const char* g) {
  __builtin_amdgcn_global_load_lds((void_g*)g, (void_l*)l, 16, 0, 0);
}

__device__ __forceinline__ float bf2f(short s) {
  union { float f; unsigned u; } v;
  v.u = ((unsigned)(unsigned short)s) << 16;
  return v.f;
}

// ---------------------------------------------------------------------------
// Kernel 1: QKV projection.
//  Qb: [N][128] bf16 row-major, pre-scaled by QSCALE
//  K3 (bf16): A-frag chunks, tile t = 32KB; chunk(jfg,kf)=1KB; lane l holds
//      K[t*128 + jfg*16 + (l&15)][kf*32 + (l>>4)*8 .. +8] at lane*16
//  V8 (fp8 e4m3), b128-paired: unit (t, sl, nfp, l15) = 16B holding
//      V[t*128+sl*8 ..+8][d=nfp*32+l15] (lo 8B) and [d=nfp*32+16+l15] (hi 8B)
// ---------------------------------------------------------------------------
__device__ __forceinline__ void mm16(const short8 (&af)[4], const float* __restrict__ W,
                                     const float* __restrict__ b, int l15, int lg,
                                     f32x4 (&acc)[8], float (&bias)[8]) {
#pragma unroll
  for (int nf = 0; nf < 8; ++nf) {
    acc[nf][0] = 0.f; acc[nf][1] = 0.f; acc[nf][2] = 0.f; acc[nf][3] = 0.f;
  }
#pragma unroll
  for (int kf = 0; kf < 4; ++kf) {
#pragma unroll
    for (int nf = 0; nf < 8; ++nf) {
      const float* wp = W + (size_t)(nf * 16 + l15) * DIM + kf * 32 + lg * 8;
      short8 bfr = pack8(*(const float4*)wp, *(const float4*)(wp + 4));
      acc[nf] = __builtin_amdgcn_mfma_f32_16x16x32_bf16(af[kf], bfr, acc[nf], 0, 0, 0);
    }
  }
#pragma unroll
  for (int nf = 0; nf < 8; ++nf) bias[nf] = b[nf * 16 + l15];
}

__global__ __launch_bounds__(256) void proj_kernel(
    const float* __restrict__ X,
    const float* __restrict__ Wq, const float* __restrict__ bq,
    const float* __restrict__ Wk, const float* __restrict__ bk,
    const float* __restrict__ Wv, const float* __restrict__ bv,
    short* __restrict__ Qb, char* __restrict__ K3, char* __restrict__ V8) {
  __shared__ short ktile[64][136];
  __shared__ short vtile[64][136];

  const int tid = threadIdx.x;
  const int w = tid >> 6, lane = tid & 63;
  const int l15 = lane & 15, lg = lane >> 4;
  const int i0 = blockIdx.x * 64;
  const int t = i0 >> 7, jl0 = i0 & 127;

  short8 af[4];
  {
    const int xrow = i0 + w * 16 + l15;
#pragma unroll
    for (int kf = 0; kf < 4; ++kf) {
      const float* xp = X + (size_t)xrow * DIM + kf * 32 + lg * 8;
      af[kf] = pack8(*(const float4*)xp, *(const float4*)(xp + 4));
    }
  }

  f32x4 acc[8];
  float bias[8];

  // ---- Q ----
  mm16(af, Wq, bq, l15, lg, acc, bias);
#pragma unroll
  for (int nf = 0; nf < 8; ++nf) {
    const int d = nf * 16 + l15;
#pragma unroll
    for (int rr = 0; rr < 4; ++rr) {
      const int i = i0 + w * 16 + lg * 4 + rr;
      Qb[(size_t)i * DIM + d] = f2bf((acc[nf][rr] + bias[nf]) * QSCALE);
    }
  }

  // ---- K ----
  mm16(af, Wk, bk, l15, lg, acc, bias);
#pragma unroll
  for (int nf = 0; nf < 8; ++nf) {
    const int d = nf * 16 + l15;
#pragma unroll
    for (int rr = 0; rr < 4; ++rr)
      ktile[w * 16 + lg * 4 + rr][d] = f2bf(acc[nf][rr] + bias[nf]);
  }

  // ---- V ----
  mm16(af, Wv, bv, l15, lg, acc, bias);
#pragma unroll
  for (int nf = 0; nf < 8; ++nf) {
    const int d = nf * 16 + l15;
#pragma unroll
    for (int rr = 0; rr < 4; ++rr)
      vtile[w * 16 + lg * 4 + rr][d] = f2bf(acc[nf][rr] + bias[nf]);
  }
  __syncthreads();

  // K3 chunks (bf16): task = chunk o (0..15) x local row (0..63)
#pragma unroll
  for (int it = 0; it < 4; ++it) {
    const int task = it * 256 + tid;
    const int o = task >> 6, jr = task & 63;
    const int j = i0 + jr;
    const int jfg = (j >> 4) & 7;
    const int kf = o >> 2, lgc = o & 3;
    short8 st = *(const short8*)&ktile[jr][o * 8];
    *(short8*)(K3 + ((size_t)((t * 8 + jfg) * 4 + kf) << 10) + lgc * 256 + (j & 15) * 16) = st;
  }

  // V8 chunks (fp8, b128-paired): task = c (8 j-octets) x d (128)
#pragma unroll
  for (int it = 0; it < 4; ++it) {
    const int task = it * 256 + tid;
    const int c = task >> 7, d = task & 127;
    float f[8];
#pragma unroll
    for (int s2 = 0; s2 < 8; ++s2) f[s2] = bf2f(vtile[c * 8 + s2][d]);
    int lo = __builtin_amdgcn_cvt_pk_fp8_f32(f[0], f[1], 0, false);
    lo = __builtin_amdgcn_cvt_pk_fp8_f32(f[2], f[3], lo, true);
    int hi = __builtin_amdgcn_cvt_pk_fp8_f32(f[4], f[5], 0, false);
    hi = __builtin_amdgcn_cvt_pk_fp8_f32(f[6], f[7], hi, true);
    const int sl = (jl0 >> 3) + c;     // j-octet index within tile (0..15)
    const int nfp = d >> 5, hi8 = (d >> 4) & 1, dl = d & 15;
    *(int2*)(V8 + (((size_t)(t * 16 + sl) * 64 + nfp * 16 + dl) * 16) + hi8 * 8)
        = make_int2(lo, hi);
  }
}

// ---------------------------------------------------------------------------
// Kernel 2: fused masked-softmax attention.
// 256 blocks x 512 threads (8 waves, 2 waves/SIMD at <=256 VGPR).
// Wave (ir, wc): i-rows [ir*32,+32) (f=0,1 sub-blocks of 16), j-slice
// [wc*32,+32). K shared across f -> K LDS reads halve. V (fp8, paired)
// prefetched to registers from L2. adj staged through LDS with rotation
// u=(c16+row*4)&31: conflict-free b128 reads + >=448B HBM segments.
// Softmax in-register (swapped QK^T + bpermute); fp8 PV (P halved).
// ---------------------------------------------------------------------------
__device__ __forceinline__ void stage_k(char* kdst, const char* __restrict__ K3,
                                        int t, int tid) {
  const char* gk = K3 + ((size_t)t << 15);
#pragma unroll
  for (int it = 0; it < 4; ++it)
    gload16(kdst + it * 8192 + tid * 16, gk + it * 8192 + tid * 16);
}

__device__ __forceinline__ void stage_adj(char* adst, const int* __restrict__ adj,
                                          int t, int i0, int tid) {
#pragma unroll
  for (int it = 0; it < 4; ++it) {
    const int s = it * 512 + tid;          // 0..2047
    const int row = s >> 5, u = s & 31;
    const int c16 = (u - row * 4) & 31;    // stored unit u holds col-unit c16
    const char* src = (const char*)(adj + (size_t)(i0 + row) * NTOK + t * 128 + c16 * 4);
    gload16(adst + it * 8192 + tid * 16, src);
  }
}

__device__ __forceinline__ void load_v(i32x4 (&v)[4], const char* __restrict__ V8,
                                       int t, int wc, int l15, int lg) {
#pragma unroll
  for (int nfp = 0; nfp < 4; ++nfp)
    v[nfp] = *(const i32x4*)(V8 + ((size_t)(t * 16 + wc * 4 + lg) * 64 + nfp * 16 + l15) * 16);
}

__device__ __forceinline__ void attn_step(
    int t, const char* kcur, const char* acur, char* knxt, char* anxt,
    const char* __restrict__ K3, const char* __restrict__ V8,
    const int* __restrict__ adj,
    const short8 (&qf)[2][4], i32x4 (&vfr)[4], f32x4 (&acc)[2][8],
    float (&dsum)[2],
    int i0, int ir, int wc, int l15, int lg, int lane, int tid,
    int ad0, bool selhi) {
  const int tn = (t + 1) & (NJT - 1);

  // stage next K tile + next adj tile (DMA); both land before next barrier
  stage_k(knxt, K3, tn, tid);
  stage_adj(anxt, adj, tn, i0, tid);

  // ---- adj(t) bits from LDS (rotated layout, conflict-free) ----
  i32x4 bits[2][2];
#pragma unroll
  for (int f = 0; f < 2; ++f)
#pragma unroll
    for (int jf = 0; jf < 2; ++jf) {
      const int rowl = ir * 32 + f * 16 + l15;
      const int u = (wc * 8 + jf * 4 + lg + rowl * 4) & 31;
      bits[f][jf] = *(const i32x4*)(acur + rowl * 512 + u * 16);
    }

  // ---- S^T = K @ Q^T : K frag shared across both f halves ----
  f32x4 sT[2][2];
#pragma unroll
  for (int f = 0; f < 2; ++f)
#pragma unroll
    for (int jf = 0; jf < 2; ++jf) {
      sT[f][jf][0] = 0.f; sT[f][jf][1] = 0.f; sT[f][jf][2] = 0.f; sT[f][jf][3] = 0.f;
    }
#pragma unroll
  for (int jf = 0; jf < 2; ++jf)
#pragma unroll
    for (int kf = 0; kf < 4; ++kf) {
      const short8 kfr = *(const short8*)(kcur + (((wc * 2 + jf) * 4 + kf) << 10) + lane * 16);
#pragma unroll
      for (int f = 0; f < 2; ++f)
        sT[f][jf] = __builtin_amdgcn_mfma_f32_16x16x32_bf16(kfr, qf[f][kf], sT[f][jf], 0, 0, 0);
    }

  // ---- mask + exp2 (halved: fp8 e4m3 max 448, max p ~508 unhalved) ----
  int pk8[2][2];
#pragma unroll
  for (int f = 0; f < 2; ++f)
#pragma unroll
    for (int jf = 0; jf < 2; ++jf) {
      const i32x4 a = bits[f][jf];
      const float p0 = a[0] ? __builtin_exp2f(sT[f][jf][0]) * 0.5f : 0.5f;
      const float p1 = a[1] ? __builtin_exp2f(sT[f][jf][1]) * 0.5f : 0.5f;
      const float p2 = a[2] ? __builtin_exp2f(sT[f][jf][2]) * 0.5f : 0.5f;
      const float p3 = a[3] ? __builtin_exp2f(sT[f][jf][3]) * 0.5f : 0.5f;
      dsum[f] += (p0 + p1) + (p2 + p3);
      int d0 = __builtin_amdgcn_cvt_pk_fp8_f32(p0, p1, 0, false);
      pk8[f][jf] = __builtin_amdgcn_cvt_pk_fp8_f32(p2, p3, d0, true);
    }

  // ---- in-wave exchange: build fp8 PV A-frags P[i=l15][j=lg*8+e] ----
  union { int2 i2; long l; } pa[2];
#pragma unroll
  for (int f = 0; f < 2; ++f)
#pragma unroll
    for (int w2 = 0; w2 < 2; ++w2) {
      const int addr = ad0 + w2 * 64;
      const int r0 = __builtin_amdgcn_ds_bpermute(addr, pk8[f][0]);
      const int r1 = __builtin_amdgcn_ds_bpermute(addr, pk8[f][1]);
      (w2 ? pa[f].i2.y : pa[f].i2.x) = selhi ? r1 : r0;
    }

  // ---- acc += P @ V (fp8 x fp8; V pairs unpacked from b128 regs) ----
#pragma unroll
  for (int nfp = 0; nfp < 4; ++nfp) {
    union { i32x4 v; long l[2]; } vv; vv.v = vfr[nfp];
#pragma unroll
    for (int f = 0; f < 2; ++f) {
      acc[f][nfp * 2]     = __builtin_amdgcn_mfma_f32_16x16x32_fp8_fp8(pa[f].l, vv.l[0], acc[f][nfp * 2], 0, 0, 0);
      acc[f][nfp * 2 + 1] = __builtin_amdgcn_mfma_f32_16x16x32_fp8_fp8(pa[f].l, vv.l[1], acc[f][nfp * 2 + 1], 0, 0, 0);
    }
  }

  // prefetch V(t+1) into registers (L2-resident; drained by the barrier)
  load_v(vfr, V8, tn, wc, l15, lg);

  // barrier: staged K/adj complete, buffers flip
  __syncthreads();
}

__global__ __launch_bounds__(512, 2) void attn_kernel(
    const short* __restrict__ QbG, const char* __restrict__ K3,
    const char* __restrict__ V8, const int* __restrict__ adj,
    float* __restrict__ out) {
  __shared__ __align__(16) char kbuf[2][32768];   // K bf16 double buffer
  __shared__ __align__(16) char abuf[2][32768];   // adj int32 double buffer

  const int tid = threadIdx.x;
  const int w = tid >> 6, lane = tid & 63;
  const int l15 = lane & 15, lg = lane >> 4;
  const int ir = w >> 2, wc = w & 3;      // ir 0..1, wc 0..3
  const int i0 = blockIdx.x * RB;

  // bpermute source lane for (w2): lg_src = (lg*2 + w2) & 3; select jf by lg>=2
  const int ad0 = 4 * (l15 + 16 * ((lg * 2) & 3));
  const bool selhi = (lg & 2) != 0;

  // Q B-frags: lane holds Q[i = i0+ir*32+f*16+l15][kf*32+lg*8 ..+8]
  short8 qf[2][4];
#pragma unroll
  for (int f = 0; f < 2; ++f) {
    const int i = i0 + ir * 32 + f * 16 + l15;
#pragma unroll
    for (int kf = 0; kf < 4; ++kf)
      qf[f][kf] = *(const short8*)(QbG + (size_t)i * DIM + kf * 32 + lg * 8);
  }

  f32x4 acc[2][8];
#pragma unroll
  for (int f = 0; f < 2; ++f)
#pragma unroll
    for (int nf = 0; nf < 8; ++nf) {
      acc[f][nf][0] = 0.f; acc[f][nf][1] = 0.f; acc[f][nf][2] = 0.f; acc[f][nf][3] = 0.f;
    }
  float dsum[2] = {0.f, 0.f};
  i32x4 vfr[4];

  stage_k(kbuf[0], K3, 0, tid);
  stage_adj(abuf[0], adj, 0, i0, tid);
  load_v(vfr, V8, 0, wc, l15, lg);
  __syncthreads();

  for (int t = 0; t < NJT; t += 2) {
    attn_step(t,     kbuf[0], abuf[0], kbuf[1], abuf[1], K3, V8, adj, qf, vfr,
              acc, dsum, i0, ir, wc, l15, lg, lane, tid, ad0, selhi);
    attn_step(t + 1, kbuf[1], abuf[1], kbuf[0], abuf[0], K3, V8, adj, qf, vfr,
              acc, dsum, i0, ir, wc, l15, lg, lane, tid, ad0, selhi);
  }

  // ---- denominator: lane covers i per f; sum over lg groups, then wc ----
  float (*denp)[64] = (float(*)[64])abuf;   // reuse adj buffer
#pragma unroll
  for (int f = 0; f < 2; ++f) {
    float v = dsum[f];
    v += __shfl_xor(v, 16);
    v += __shfl_xor(v, 32);
    if (lg == 0) denp[wc][ir * 32 + f * 16 + l15] = v;
  }

  // ---- cross-wc acc reduction through LDS (reuse kbuf: 33.8KB) ----
  float* red = (float*)kbuf;   // 2 ir-slots x 32 rows x 132 floats
#pragma unroll
  for (int rnd = 1; rnd <= 3; ++rnd) {
    __syncthreads();
    if (wc == rnd) {
      const int base = ir * 32 * 132;
#pragma unroll
      for (int f = 0; f < 2; ++f)
#pragma unroll
        for (int nf = 0; nf < 8; ++nf)
#pragma unroll
          for (int r = 0; r < 4; ++r)
            red[base + (f * 16 + lg * 4 + r) * 132 + nf * 16 + l15] = acc[f][nf][r];
    }
    __syncthreads();
    if (wc == 0) {
      const int base = ir * 32 * 132;
#pragma unroll
      for (int f = 0; f < 2; ++f)
#pragma unroll
        for (int nf = 0; nf < 8; ++nf)
#pragma unroll
          for (int r = 0; r < 4; ++r)
            acc[f][nf][r] += red[base + (f * 16 + lg * 4 + r) * 132 + nf * 16 + l15];
    }
  }

  if (wc == 0) {
#pragma unroll
    for (int f = 0; f < 2; ++f) {
      float den[4];
#pragma unroll
      for (int r = 0; r < 4; ++r) {
        const int il = ir * 32 + f * 16 + lg * 4 + r;
        den[r] = (denp[0][il] + denp[1][il]) + (denp[2][il] + denp[3][il]);
      }
#pragma unroll
      for (int nf = 0; nf < 8; ++nf)
#pragma unroll
        for (int r = 0; r < 4; ++r) {
          const int i = ir * 32 + f * 16 + lg * 4 + r;
          out[(size_t)(i0 + i) * DIM + nf * 16 + l15] = acc[f][nf][r] / den[r];
        }
    }
  }
}

// ---------------------------------------------------------------------------
extern "C" void kernel_launch(void* const* d_in, const int* in_sizes, int n_in,
                              void* d_out, int out_size, void* d_ws, size_t ws_size,
                              hipStream_t stream) {
  const float* X  = (const float*)d_in[0];
  const float* Wq = (const float*)d_in[1];
  const float* bq = (const float*)d_in[2];
  const float* Wk = (const float*)d_in[3];
  const float* bk = (const float*)d_in[4];
  const float* Wv = (const float*)d_in[5];
  const float* bv = (const float*)d_in[6];
  const int*  adj = (const int*)d_in[7];
  float* out = (float*)d_out;

  char* ws = (char*)d_ws;
  short* Qb = (short*)ws;                       // 4 MB bf16 [N][128]
  char*  K3 = ws + ((size_t)4 << 20);           // 4 MB A-frag-contiguous K (bf16)
  char*  V8 = ws + ((size_t)8 << 20);           // 2 MB fp8 V^T paired chunks

  proj_kernel<<<256, 256, 0, stream>>>(X, Wq, bq, Wk, bk, Wv, bv, Qb, K3, V8);
  attn_kernel<<<256, 512, 0, stream>>>(Qb, K3, V8, adj, out);
}